// Round 14
// baseline (516.179 us; speedup 1.0000x reference)
//
#include <hip/hip_runtime.h>
#include <math.h>

#define H 64
#define F 16
#define NUM_G 128
#define DPW 8
#define NBLK 512     // segments for bucket partition
#define SORTB 256    // dst-range buckets
#define L2E 1.4426950408889634f
#define TWO_L2E 2.8853900817779268f

__device__ __forceinline__ int lower_bound_i(const int* a, int n, int key) {
    int lo = 0, hi = n;
    while (lo < hi) { int mid = (lo + hi) >> 1; if (a[mid] < key) lo = mid + 1; else hi = mid; }
    return lo;
}

__device__ __forceinline__ unsigned bf16rne(float f) {
    unsigned u = __float_as_uint(f);
    return (u + 0x7fffu + ((u >> 16) & 1u)) >> 16;
}

__device__ __forceinline__ unsigned sel8u(unsigned a0, unsigned a1, unsigned a2, unsigned a3,
                                          unsigned a4, unsigned a5, unsigned a6, unsigned a7, int i) {
    unsigned b0 = (i & 1) ? a1 : a0, b1 = (i & 1) ? a3 : a2;
    unsigned b2 = (i & 1) ? a5 : a4, b3 = (i & 1) ? a7 : a6;
    unsigned c0 = (i & 2) ? b1 : b0, c1 = (i & 2) ? b3 : b2;
    return (i & 4) ? c1 : c0;
}
__device__ __forceinline__ int sel8i(int a0, int a1, int a2, int a3,
                                     int a4, int a5, int a6, int a7, int i) {
    int b0 = (i & 1) ? a1 : a0, b1 = (i & 1) ? a3 : a2;
    int b2 = (i & 1) ? a5 : a4, b3 = (i & 1) ? a7 : a6;
    int c0 = (i & 2) ? b1 : b0, c1 = (i & 2) ? b3 : b2;
    return (i & 4) ? c1 : c0;
}

// ---------------- projection section descriptor ----------------
struct ProjSec {
    const float* x; const float* Wa; const float* ba;
    const float* Wb; const float* bb2; unsigned* out;
    int N; int waveOff; float scaleA;
};
#define PROJ_ROWS 16

__device__ __forceinline__ void proj_rows(const ProjSec& S, int w, int lane) {
    const int r0 = (w - S.waveOff) * PROJ_ROWS;
    float wa[F], wb[F];
#pragma unroll
    for (int f = 0; f < F; ++f) {
        wa[f] = S.Wa[f * H + lane] * S.scaleA;
        wb[f] = S.Wb[f * H + lane];
    }
    const float bah = S.ba[lane] * S.scaleA, bbh = S.bb2[lane];
    int r1e = r0 + PROJ_ROWS; if (r1e > S.N) r1e = S.N;
    for (int n = r0; n < r1e; ++n) {
        const float4* xr = (const float4*)(S.x + (size_t)n * F);
        float a = bah, b = bbh;
#pragma unroll
        for (int f4 = 0; f4 < F / 4; ++f4) {
            float4 t = xr[f4];
            a = fmaf(t.x, wa[4*f4+0], a); a = fmaf(t.y, wa[4*f4+1], a);
            a = fmaf(t.z, wa[4*f4+2], a); a = fmaf(t.w, wa[4*f4+3], a);
            b = fmaf(t.x, wb[4*f4+0], b); b = fmaf(t.y, wb[4*f4+1], b);
            b = fmaf(t.z, wb[4*f4+2], b); b = fmaf(t.w, wb[4*f4+3], b);
        }
        S.out[(size_t)n * H + lane] = bf16rne(a) | (bf16rne(b) << 16);
    }
}

// ---------------- fused bucket-histogram (+btot atomics) + 4-section projections ----------------
__global__ __launch_bounds__(256) void bhist_proj_kernel(
    const int* __restrict__ dst0, int E0,
    const int* __restrict__ dst1, int E1n, int dstOff1,
    int perB, int* __restrict__ bhist, int* __restrict__ btot,
    ProjSec s0, ProjSec s1, ProjSec s2, ProjSec s3, int wTot)
{
    if ((int)blockIdx.x < NBLK) {
        __shared__ int c[SORTB];
        if (threadIdx.x < SORTB) c[threadIdx.x] = 0;
        __syncthreads();
        const long ET = (long)E0 + E1n;
        const long e0 = ET * blockIdx.x / NBLK;
        const long e1 = ET * (blockIdx.x + 1) / NBLK;
        for (long i = e0 + threadIdx.x; i < e1; i += 256) {
            int d = (i < E0) ? __builtin_nontemporal_load(dst0 + i)
                             : dstOff1 + __builtin_nontemporal_load(dst1 + (i - E0));
            atomicAdd(&c[(unsigned)d / (unsigned)perB], 1);
        }
        __syncthreads();
        if (threadIdx.x < SORTB) {
            bhist[threadIdx.x * NBLK + blockIdx.x] = c[threadIdx.x];
            atomicAdd(&btot[threadIdx.x], c[threadIdx.x]);
        }
        return;
    }
    const int lane = threadIdx.x & 63;
    const int w = ((int)blockIdx.x - NBLK) * 4 + (threadIdx.x >> 6);
    if (w >= wTot) return;
    ProjSec S = (w >= s3.waveOff) ? s3 : (w >= s2.waveOff) ? s2 : (w >= s1.waveOff) ? s1 : s0;
    proj_rows(S, w, lane);
}

// ---------------- fallback: fused per-dst hist + projections ----------------
__global__ __launch_bounds__(256) void hist_proj_kernel(
    const int* __restrict__ dst0, int E0,
    const int* __restrict__ dst1, int E1n, int dstOff1,
    int* __restrict__ cnt, int histBlocks,
    ProjSec s0, ProjSec s1, ProjSec s2, ProjSec s3, int wTot)
{
    if ((int)blockIdx.x < histBlocks) {
        int i = blockIdx.x * blockDim.x + threadIdx.x;
        if (i < E0) {
            atomicAdd(&cnt[dst0[i]], 1);
        } else {
            i -= E0;
            if (i < E1n) atomicAdd(&cnt[dstOff1 + dst1[i]], 1);
        }
        return;
    }
    const int lane = threadIdx.x & 63;
    const int w = ((int)blockIdx.x - histBlocks) * 4 + (threadIdx.x >> 6);
    if (w >= wTot) return;
    ProjSec S = (w >= s3.waveOff) ? s3 : (w >= s2.waveOff) ? s2 : (w >= s1.waveOff) ? s1 : s0;
    proj_rows(S, w, lane);
}

// ---------------- scan bucket totals (257 entries, in place) ----------------
__global__ __launch_bounds__(256) void btot_scan_kernel(int* __restrict__ bs)
{
    __shared__ int sh[256];
    const int t = threadIdx.x;
    const int v = bs[t];
    sh[t] = v;
    __syncthreads();
    for (int off = 1; off < 256; off <<= 1) {
        int x = sh[t];
        int add = (t >= off) ? sh[t - off] : 0;
        __syncthreads();
        sh[t] = x + add;
        __syncthreads();
    }
    bs[t] = sh[t] - v;              // exclusive
    if (t == 255) bs[256] = sh[255];
}

// ---------------- per-bucket scan over blocks ----------------
__global__ __launch_bounds__(256) void bhist_scan_kernel(int* __restrict__ bhist,
                                                         const int* __restrict__ bucketStart)
{
    const int o = blockIdx.x, t = threadIdx.x;
    int v0 = bhist[o * NBLK + 2 * t];
    int v1 = bhist[o * NBLK + 2 * t + 1];
    __shared__ int part[256];
    part[t] = v0 + v1;
    __syncthreads();
    for (int off = 1; off < 256; off <<= 1) {
        int v = part[t];
        int add = (t >= off) ? part[t - off] : 0;
        __syncthreads();
        part[t] = v + add;
        __syncthreads();
    }
    int excl = (t == 0) ? 0 : part[t - 1];
    const int base = bucketStart[o];
    bhist[o * NBLK + 2 * t] = base + excl;
    bhist[o * NBLK + 2 * t + 1] = base + excl + v0;
}

// ---------------- deterministic bucket partition (8B packed tuples) ----------------
// tuple.x = s | (dlocal << 18)   (requires srcTot < 2^18, perB < 2^11 — checked host-side)
__global__ __launch_bounds__(256) void bscatter_kernel(
    const int* __restrict__ src0, const int* __restrict__ dst0,
    const float* __restrict__ ea0, int E0,
    const int* __restrict__ src1, const int* __restrict__ dst1,
    const float* __restrict__ ea1, int E1n,
    int dstOff1, int srcOff1, int perB,
    const int* __restrict__ bhist,
    int2* __restrict__ t_se)
{
    __shared__ int cur[SORTB];
    if (threadIdx.x < SORTB)
        cur[threadIdx.x] = bhist[threadIdx.x * NBLK + blockIdx.x];
    __syncthreads();
    const long ET = (long)E0 + E1n;
    const long e0 = ET * blockIdx.x / NBLK;
    const long e1 = ET * (blockIdx.x + 1) / NBLK;
    for (long i = e0 + threadIdx.x; i < e1; i += 256) {
        int s, d; float e;
        if (i < E0) {
            s = __builtin_nontemporal_load(src0 + i);
            d = __builtin_nontemporal_load(dst0 + i);
            e = __builtin_nontemporal_load(ea0 + i);
        } else {
            long j = i - E0;
            s = __builtin_nontemporal_load(src1 + j) + srcOff1;
            d = __builtin_nontemporal_load(dst1 + j) + dstOff1;
            e = __builtin_nontemporal_load(ea1 + j);
        }
        int o = (unsigned)d / (unsigned)perB;
        int dlocal = d - o * perB;
        int slot = atomicAdd(&cur[o], 1);     // LDS atomic
        t_se[slot] = make_int2(s | (dlocal << 18), __float_as_int(e));
    }
}

// ---------------- per-bucket LDS sort -> offsets + meta ----------------
__global__ __launch_bounds__(256) void bucket_sort_kernel(
    const int2* __restrict__ t_se,
    const int* __restrict__ bucketStart, int NT, int perB,
    int* __restrict__ offsets, int2* __restrict__ meta)
{
    extern __shared__ int lds[];     // cnt[perB] | part[256]
    int* cnt = lds;
    int* part = lds + perB;
    const int o = blockIdx.x, t = threadIdx.x;
    int dlo = o * perB; if (dlo > NT) dlo = NT;
    int dhi = dlo + perB; if (dhi > NT) dhi = NT;
    const int nd = dhi - dlo;
    for (int i = t; i < nd; i += 256) cnt[i] = 0;
    __syncthreads();
    const int b0 = bucketStart[o], b1 = bucketStart[o + 1];
    for (int i = b0 + t; i < b1; i += 256)
        atomicAdd(&cnt[(unsigned)t_se[i].x >> 18], 1);
    __syncthreads();
    const int C = (nd + 255) / 256;
    const int lo = t * C;
    int hi = lo + C; if (hi > nd) hi = nd;
    int s = 0;
    for (int j = lo; j < hi; ++j) s += cnt[j];
    part[t] = s;
    __syncthreads();
    for (int off = 1; off < 256; off <<= 1) {
        int v = part[t];
        int add = (t >= off) ? part[t - off] : 0;
        __syncthreads();
        part[t] = v + add;
        __syncthreads();
    }
    int run = (t == 0) ? 0 : part[t - 1];
    for (int j = lo; j < hi; ++j) { int v = cnt[j]; cnt[j] = run; run += v; }
    __syncthreads();
    for (int i = t; i < nd; i += 256) offsets[dlo + i] = b0 + cnt[i];
    if (dhi == NT && t == 0) offsets[NT] = b1;
    __syncthreads();
    for (int i = b0 + t; i < b1; i += 256) {
        int2 se = t_se[i];
        int dl = (unsigned)se.x >> 18;
        int slot = b0 + atomicAdd(&cnt[dl], 1);
        meta[slot] = make_int2(se.x & 0x3FFFF, se.y);
    }
}

// ---------------- fallback global scan + scatter ----------------
__global__ __launch_bounds__(256) void scan_partial(const int* __restrict__ cnt,
                                                    int* __restrict__ bsums, int n) {
    __shared__ int red[256];
    const int b = blockIdx.x, t = threadIdx.x;
    const int base = b * 2048 + t * 8;
    int s = 0;
#pragma unroll
    for (int i = 0; i < 8; ++i) { int idx = base + i; if (idx < n) s += cnt[idx]; }
    red[t] = s;
    __syncthreads();
    for (int off = 128; off > 0; off >>= 1) {
        if (t < off) red[t] += red[t + off];
        __syncthreads();
    }
    if (t == 0) bsums[b] = red[0];
}

__global__ __launch_bounds__(256) void scan_bsums(int* __restrict__ bsums, int nb) {
    __shared__ int sh[256];
    const int t = threadIdx.x;
    sh[t] = (t < nb) ? bsums[t] : 0;
    __syncthreads();
    for (int off = 1; off < 256; off <<= 1) {
        int v = sh[t];
        int add = (t >= off) ? sh[t - off] : 0;
        __syncthreads();
        sh[t] = v + add;
        __syncthreads();
    }
    if (t < nb) bsums[t] = (t == 0) ? 0 : sh[t - 1];
}

__global__ __launch_bounds__(256) void scan_final(int* __restrict__ cnt,
                                                  const int* __restrict__ bsums,
                                                  int* __restrict__ offsets, int n) {
    __shared__ int red[256];
    const int b = blockIdx.x, t = threadIdx.x;
    const int base = b * 2048 + t * 8;
    int v[8]; int s = 0;
#pragma unroll
    for (int i = 0; i < 8; ++i) { int idx = base + i; v[i] = (idx < n) ? cnt[idx] : 0; s += v[i]; }
    red[t] = s;
    __syncthreads();
    for (int off = 1; off < 256; off <<= 1) {
        int val = red[t];
        int add = (t >= off) ? red[t - off] : 0;
        __syncthreads();
        red[t] = val + add;
        __syncthreads();
    }
    const int ex = (t == 0) ? 0 : red[t - 1];
    int run = bsums[b] + ex;
#pragma unroll
    for (int i = 0; i < 8; ++i) {
        int idx = base + i;
        if (idx < n) { offsets[idx] = run; cnt[idx] = run; }
        run += v[i];
    }
    if (t == 255 && b == gridDim.x - 1) offsets[n] = run;
}

__device__ __forceinline__ void scat_sub(
    const int* __restrict__ src, const int* __restrict__ dst,
    const float* __restrict__ ea, long lo, long hi,
    int dstOff, int srcOff, int dlo, int dhi,
    int* __restrict__ cursor, int2* __restrict__ meta, int tid)
{
    for (long i = lo + tid; i < hi; i += 256) {
        int d = dstOff + __builtin_nontemporal_load(dst + i);
        if (d >= dlo && d < dhi) {
            int s = __builtin_nontemporal_load(src + i) + srcOff;
            float e = __builtin_nontemporal_load(ea + i);
            int p = atomicAdd(&cursor[d], 1);
            meta[p] = make_int2(s, __float_as_int(e));
        }
    }
}

__global__ __launch_bounds__(256) void scatter_part_kernel(
    const int* __restrict__ src0, const int* __restrict__ dst0,
    const float* __restrict__ ea0, int E0,
    const int* __restrict__ src1, const int* __restrict__ dst1,
    const float* __restrict__ ea1, int E1n,
    int dstOff1, int srcOff1, int NTd,
    int* __restrict__ cursor, int2* __restrict__ meta)
{
    const int grp = blockIdx.x & 7;
    const int seg = blockIdx.x >> 3;
    const int nseg = gridDim.x >> 3;
    const int per = (NTd + 7) >> 3;
    const int dlo = grp * per;
    int dhi = dlo + per; if (dhi > NTd) dhi = NTd;
    if (dlo >= dhi) return;
    const long ET = (long)E0 + E1n;
    const long e0 = (ET * seg) / nseg;
    const long e1 = (ET * (seg + 1)) / nseg;
    const int tid = threadIdx.x;
    long a0 = e0, a1 = (e1 < E0) ? e1 : E0;
    if (a0 < a1) scat_sub(src0, dst0, ea0, a0, a1, 0, 0, dlo, dhi, cursor, meta, tid);
    long b0 = (e0 > E0) ? e0 : E0, b1 = e1;
    if (b0 < b1) scat_sub(src1, dst1, ea1, b0 - E0, b1 - E0, dstOff1, srcOff1,
                          dlo, dhi, cursor, meta, tid);
}

// ---------------- deep-pipelined streaming aggregate (v4b: 4 groups in flight) ----------------
struct RelP {
    const float* We; const float* be;
    const int* batch;
    float* psum;
    int Ndst;
    int offBase;
    int kskBase;
};

__global__ __launch_bounds__(256) void aggregate_v4(
    RelP P0, RelP P1, const unsigned* __restrict__ qvp,
    const unsigned* __restrict__ kskp,
    const int* __restrict__ offsets, const int2* __restrict__ meta,
    int nChunk0, int chunkHi)
{
    const int lane = threadIdx.x & 63;
    const int cid = blockIdx.x * (blockDim.x >> 6) + (threadIdx.x >> 6);
    if (cid >= chunkHi) return;
    const bool r1v = (cid >= nChunk0);
    const RelP P = r1v ? P1 : P0;
    const int dLo = (r1v ? cid - nChunk0 : cid) * DPW;
    if (dLo >= P.Ndst) return;
    const int ndst = (P.Ndst - dLo < DPW) ? (P.Ndst - dLo) : DPW;

    const float weh = P.We[lane], beh = P.be[lane];

    const int* ob = offsets + P.offBase + dLo;
    const int* bb_ = P.batch + dLo;
    int of0, of1, of2, of3, of4, of5, of6, of7, of8;
    int bg0, bg1, bg2, bg3, bg4, bg5, bg6, bg7;
#define LDO(I) __builtin_amdgcn_readfirstlane(ob[(I) < ndst ? (I) : ndst])
#define LDB(I) __builtin_amdgcn_readfirstlane(bb_[(I) < ndst ? (I) : (ndst - 1)])
    of0 = LDO(0); of1 = LDO(1); of2 = LDO(2); of3 = LDO(3); of4 = LDO(4);
    of5 = LDO(5); of6 = LDO(6); of7 = LDO(7); of8 = LDO(8);
    bg0 = LDB(0); bg1 = LDB(1); bg2 = LDB(2); bg3 = LDB(3);
    bg4 = LDB(4); bg5 = LDB(5); bg6 = LDB(6); bg7 = LDB(7);
#undef LDO
#undef LDB

    const unsigned* kb = kskp + (size_t)(P.kskBase + dLo) * H + lane;
    unsigned kp0 = kb[0], kp1 = 0, kp2 = 0, kp3 = 0, kp4 = 0, kp5 = 0, kp6 = 0, kp7 = 0;
    if (ndst > 1) kp1 = kb[1 * H];
    if (ndst > 2) kp2 = kb[2 * H];
    if (ndst > 3) kp3 = kb[3 * H];
    if (ndst > 4) kp4 = kb[4 * H];
    if (ndst > 5) kp5 = kb[5 * H];
    if (ndst > 6) kp6 = kb[6 * H];
    if (ndst > 7) kp7 = kb[7 * H];

    int idx = 0;
    float kcur = __uint_as_float(kp0 << 16);
    float skcur = __uint_as_float(kp0 & 0xffff0000u);
    int pend = of1;
    int bgcur = bg0;
    float acc = 0.f;
    const int base = of0;
    const int pstop = of8;
    const int nedges = pstop - base;
    const int ngroups = (nedges + 7) >> 3;

#define ADVANCE()                                                              \
    {                                                                          \
        float hv = fmaxf(acc + skcur, 0.f);                                    \
        atomicAdd(&P.psum[(size_t)bgcur * H + lane], hv);                      \
        ++idx;                                                                 \
        unsigned kv = sel8u(kp0, kp1, kp2, kp3, kp4, kp5, kp6, kp7, idx);      \
        kcur = __uint_as_float(kv << 16);                                      \
        skcur = __uint_as_float(kv & 0xffff0000u);                             \
        pend = sel8i(of1, of2, of3, of4, of5, of6, of7, of8, idx);             \
        bgcur = sel8i(bg0, bg1, bg2, bg3, bg4, bg5, bg6, bg7, idx);            \
        acc = 0.f;                                                             \
    }

#define ISSUE(RING, M, L8, GI)                                                 \
    if ((GI) < ngroups) {                                                      \
        _Pragma("unroll")                                                      \
        for (int j = 0; j < 8; ++j) {                                          \
            int s_ = __builtin_amdgcn_readlane((M).x, (L8) + j);               \
            RING[j] = qvp[(size_t)(unsigned)s_ * H + lane];                    \
        }                                                                      \
    }

#define CONSUME(RING, L8, GI)                                                  \
    if ((GI) < ngroups) {                                                      \
        const int e0 = (GI) * 8;                                               \
        int n_ = nedges - e0; if (n_ > 8) n_ = 8;                              \
        _Pragma("unroll")                                                      \
        for (int j = 0; j < 8; ++j) {                                          \
            if (j < n_) {                                                      \
                while (base + e0 + j >= pend) ADVANCE();                       \
                float e = fmaf(__int_as_float(                                 \
                    __builtin_amdgcn_readlane(Mc.y, (L8) + j)), weh, beh);     \
                float qq = __uint_as_float(RING[j] << 16);                     \
                float vv = __uint_as_float(RING[j] & 0xffff0000u);             \
                float g2 = fmaf(TWO_L2E, e, kcur + qq);                        \
                float sg = __builtin_amdgcn_rcpf(1.0f + __builtin_amdgcn_exp2f(-g2)); \
                acc = fmaf(sg, vv + e, acc);                                   \
            }                                                                  \
        }                                                                      \
    }

    if (nedges > 0) {
        int pos0 = base + lane; if (pos0 > pstop - 1) pos0 = pstop - 1;
        int2 Mc = meta[pos0];
        int2 Mn = Mc;
        if (nedges > 64) {
            int pos1 = base + 64 + lane; if (pos1 > pstop - 1) pos1 = pstop - 1;
            Mn = meta[pos1];
        }
        unsigned r0[8], r1[8], r2[8], r3[8];
        // 4-deep prologue: groups 0..3 in flight before first consume
        ISSUE(r0, Mc, 0,  0);
        ISSUE(r1, Mc, 8,  1);
        ISSUE(r2, Mc, 16, 2);
        ISSUE(r3, Mc, 24, 3);
        const int nsb = (ngroups + 7) >> 3;
        int sbg = 0;
        for (int sbi = 0; sbi < nsb; ++sbi, sbg += 8) {
            CONSUME(r0, 0,  sbg + 0); ISSUE(r0, Mc, 32, sbg + 4);
            CONSUME(r1, 8,  sbg + 1); ISSUE(r1, Mc, 40, sbg + 5);
            CONSUME(r2, 16, sbg + 2); ISSUE(r2, Mc, 48, sbg + 6);
            CONSUME(r3, 24, sbg + 3); ISSUE(r3, Mc, 56, sbg + 7);
            CONSUME(r0, 32, sbg + 4); ISSUE(r0, Mn, 0,  sbg + 8);
            CONSUME(r1, 40, sbg + 5); ISSUE(r1, Mn, 8,  sbg + 9);
            CONSUME(r2, 48, sbg + 6); ISSUE(r2, Mn, 16, sbg + 10);
            CONSUME(r3, 56, sbg + 7); ISSUE(r3, Mn, 24, sbg + 11);
            Mc = Mn;
            if ((sbi + 2) * 64 < nedges) {
                int pos = base + (sbi + 2) * 64 + lane;
                if (pos > pstop - 1) pos = pstop - 1;
                Mn = meta[pos];
            }
        }
    }
#undef ISSUE
#undef CONSUME

    for (;;) {
        float hv = fmaxf(acc + skcur, 0.f);
        atomicAdd(&P.psum[(size_t)bgcur * H + lane], hv);
        ++idx;
        if (idx >= ndst) break;
        unsigned kv = sel8u(kp0, kp1, kp2, kp3, kp4, kp5, kp6, kp7, idx);
        kcur = __uint_as_float(kv << 16);
        skcur = __uint_as_float(kv & 0xffff0000u);
        bgcur = sel8i(bg0, bg1, bg2, bg3, bg4, bg5, bg6, bg7, idx);
        acc = 0.f;
    }
#undef ADVANCE
}

// ---------------- MLP with fused per-graph counts ----------------
__global__ __launch_bounds__(64) void mlp_kernel(
    const float* __restrict__ sum_c, const float* __restrict__ sum_b,
    const int* __restrict__ batch_c, int Nc,
    const int* __restrict__ batch_b, int Nb,
    const float* __restrict__ W1, const float* __restrict__ b1,
    const float* __restrict__ W2, const float* __restrict__ b2,
    const float* __restrict__ W3, const float* __restrict__ b3,
    const float* __restrict__ Wout, const float* __restrict__ bout,
    float* __restrict__ out)
{
    const int g = blockIdx.x;
    const int h = threadIdx.x;
    __shared__ float pld[2 * H];
    __shared__ float hbuf[H];
    __shared__ float cnts[2];
    if (h < 2) {
        const int* a = h ? batch_b : batch_c;
        const int n = h ? Nb : Nc;
        int lo = lower_bound_i(a, n, g);
        int hi = lower_bound_i(a, n, g + 1);
        cnts[h] = fmaxf((float)(hi - lo), 1.f);
    }
    __syncthreads();
    pld[h] = sum_c[g * H + h] / cnts[0];
    pld[H + h] = sum_b[g * H + h] / cnts[1];
    __syncthreads();
    float a1 = b1[h];
    for (int j = 0; j < 2 * H; ++j) a1 = fmaf(pld[j], W1[j * H + h], a1);
    a1 = fmaxf(a1, 0.f);
    __syncthreads();
    hbuf[h] = a1;
    __syncthreads();
    float a2 = b2[h];
    for (int j = 0; j < H; ++j) a2 = fmaf(hbuf[j], W2[j * H + h], a2);
    a2 = fmaxf(a2, 0.f);
    __syncthreads();
    hbuf[h] = a2;
    __syncthreads();
    float a3 = b3[h];
    for (int j = 0; j < H; ++j) a3 = fmaf(hbuf[j], W3[j * H + h], a3);
    a3 = fmaxf(a3, 0.f);
    float p = a3 * Wout[h];
#pragma unroll
    for (int off = 32; off > 0; off >>= 1) p += __shfl_down(p, off, 64);
    if (h == 0) out[g] = p + bout[0];
}

extern "C" void kernel_launch(void* const* d_in, const int* in_sizes, int n_in,
                              void* d_out, int out_size, void* d_ws, size_t ws_size,
                              hipStream_t stream) {
    const float* x_x   = (const float*)d_in[0];
    const float* x_c   = (const float*)d_in[1];
    const float* x_b   = (const float*)d_in[2];
    const float* ea_ac = (const float*)d_in[3];
    const float* ea_cb = (const float*)d_in[4];

    const float* Wk_ac = (const float*)d_in[5];
    const float* Wq_ac = (const float*)d_in[6];
    const float* Wv_ac = (const float*)d_in[7];
    const float* Wskip_ac = (const float*)d_in[8];
    const float* We_ac = (const float*)d_in[9];
    const float* bk_ac = (const float*)d_in[10];
    const float* bq_ac = (const float*)d_in[11];
    const float* bv_ac = (const float*)d_in[12];
    const float* be_ac = (const float*)d_in[13];
    const float* bconv_ac = (const float*)d_in[14];

    const float* Wk_cb = (const float*)d_in[15];
    const float* Wq_cb = (const float*)d_in[16];
    const float* Wv_cb = (const float*)d_in[17];
    const float* Wskip_cb = (const float*)d_in[18];
    const float* We_cb = (const float*)d_in[19];
    const float* bk_cb = (const float*)d_in[20];
    const float* bq_cb = (const float*)d_in[21];
    const float* bv_cb = (const float*)d_in[22];
    const float* be_cb = (const float*)d_in[23];
    const float* bconv_cb = (const float*)d_in[24];

    const float* W1 = (const float*)d_in[25];
    const float* b1 = (const float*)d_in[26];
    const float* W2 = (const float*)d_in[27];
    const float* b2 = (const float*)d_in[28];
    const float* W3 = (const float*)d_in[29];
    const float* b3 = (const float*)d_in[30];
    const float* Wout = (const float*)d_in[31];
    const float* bout = (const float*)d_in[32];

    const int* src_ac = (const int*)d_in[33];
    const int* dst_ac = (const int*)d_in[34];
    const int* src_cb = (const int*)d_in[35];
    const int* dst_cb = (const int*)d_in[36];
    const int* batch_c = (const int*)d_in[37];
    const int* batch_b = (const int*)d_in[38];

    const int Nx = in_sizes[0] / F;
    const int Nc = in_sizes[1] / F;
    const int Nb = in_sizes[2] / F;
    const int E1 = in_sizes[33];
    const int E2 = in_sizes[35];
    (void)n_in; (void)out_size;

    const int NT = Nc + Nb;
    const size_t ET = (size_t)E1 + E2;
    const size_t SUMS = 2 * NUM_G * H;
    const int perB = (NT + SORTB - 1) / SORTB;

    // layout (words):
    // meta 2ET | offsets NT+1 | bucketStart 257 | sum_c | sum_b
    // | qvp (Nx+Nc)*H | kskp (Nc+Nb)*H | t_se 2ET (8B packed) | bhist SORTB*NBLK
    // fallback-only: cnt/bsums overlay t_se space.
    const size_t qvW  = (size_t)(Nx + Nc) * H;
    const size_t kskW = (size_t)(Nc + Nb) * H;
    const size_t head = 2 * ET + (size_t)(NT + 1) + 257 + SUMS + qvW + kskW;
    const size_t tOff = (head + 1) & ~(size_t)1;
    const size_t wordsB = tOff + 2 * ET + (size_t)SORTB * NBLK;
    const size_t wordsA = head + (size_t)NT + 256;      // fallback overlays cnt/bsums
    const bool packOK = ((Nx + Nc) <= (1 << 18)) && (perB <= (1 << 11));
    const bool pathA = (ws_size >= wordsA * 4);
    const bool pathB = (ws_size >= wordsB * 4) && packOK;

    int* ws = (int*)d_ws;
    int2*     meta        = (int2*)ws;
    int*      offsets     = ws + 2 * ET;
    int*      bucketStart = offsets + (NT + 1);
    float*    sum_c       = (float*)(bucketStart + 257);
    float*    sum_b       = sum_c + NUM_G * H;
    unsigned* qvp         = (unsigned*)(sum_b + NUM_G * H);
    unsigned* kskp        = qvp + qvW;
    int2*     t_se        = (int2*)(ws + tOff);
    int*      bhist       = (int*)(t_se + ET);
    int*      cnt         = (int*)t_se;          // fallback overlay
    int*      bsums       = cnt + NT;            // fallback overlay

    const int nC0 = (Nc + DPW - 1) / DPW;
    const int nC1 = (Nb + DPW - 1) / DPW;

    RelP P0, P1;
    P0.We = We_ac; P0.be = be_ac; P0.batch = batch_c; P0.psum = sum_c;
    P0.Ndst = Nc; P0.offBase = 0; P0.kskBase = 0;
    P1.We = We_cb; P1.be = be_cb; P1.batch = batch_b; P1.psum = sum_b;
    P1.Ndst = Nb; P1.offBase = Nc; P1.kskBase = Nc;

    if (pathA) {
        const int w1 = (Nx + PROJ_ROWS - 1) / PROJ_ROWS;
        const int w2 = w1 + (Nc + PROJ_ROWS - 1) / PROJ_ROWS;
        const int w3 = w2 + (Nc + PROJ_ROWS - 1) / PROJ_ROWS;
        const int wTot = w3 + (Nb + PROJ_ROWS - 1) / PROJ_ROWS;
        ProjSec s0 = { x_x, Wq_ac, bq_ac, Wv_ac, bv_ac, qvp, Nx, 0, L2E };
        ProjSec s1 = { x_c, Wq_cb, bq_cb, Wv_cb, bv_cb, qvp + (size_t)Nx * H, Nc, w1, L2E };
        ProjSec s2 = { x_c, Wk_ac, bk_ac, Wskip_ac, bconv_ac, kskp, Nc, w2, L2E };
        ProjSec s3 = { x_b, Wk_cb, bk_cb, Wskip_cb, bconv_cb, kskp + (size_t)Nc * H, Nb, w3, L2E };
        const int projB = (wTot + 3) / 4;

        if (pathB) {
            hipMemsetAsync(bucketStart, 0, (257 + SUMS) * sizeof(int), stream);
            bhist_proj_kernel<<<NBLK + projB, 256, 0, stream>>>(
                dst_ac, E1, dst_cb, E2, Nc, perB, bhist, bucketStart,
                s0, s1, s2, s3, wTot);
            btot_scan_kernel<<<1, 256, 0, stream>>>(bucketStart);
            bhist_scan_kernel<<<SORTB, 256, 0, stream>>>(bhist, bucketStart);
            bscatter_kernel<<<NBLK, 256, 0, stream>>>(
                src_ac, dst_ac, ea_ac, E1, src_cb, dst_cb, ea_cb, E2,
                Nc, Nx, perB, bhist, t_se);
            bucket_sort_kernel<<<SORTB, 256, (perB + 257) * sizeof(int), stream>>>(
                t_se, bucketStart, NT, perB, offsets, meta);
        } else {
            hipMemsetAsync(bucketStart, 0, (257 + SUMS) * sizeof(int), stream);
            hipMemsetAsync(cnt, 0, (size_t)(NT + 256) * sizeof(int), stream);
            const int nScan = (NT + 2047) / 2048;
            const int EB = (int)((ET + 255) / 256);
            hist_proj_kernel<<<EB + projB, 256, 0, stream>>>(
                dst_ac, E1, dst_cb, E2, Nc, cnt, EB, s0, s1, s2, s3, wTot);
            scan_partial<<<nScan, 256, 0, stream>>>(cnt, bsums, NT);
            scan_bsums<<<1, 256, 0, stream>>>(bsums, nScan);
            scan_final<<<nScan, 256, 0, stream>>>(cnt, bsums, offsets, NT);
            scatter_part_kernel<<<2048, 256, 0, stream>>>(
                src_ac, dst_ac, ea_ac, E1, src_cb, dst_cb, ea_cb, E2,
                Nc, Nx, NT, cnt, meta);
        }

        const int nW = nC0 + nC1;
        aggregate_v4<<<(nW + 3) / 4, 256, 0, stream>>>(
            P0, P1, qvp, kskp, offsets, meta, nC0, nW);

        mlp_kernel<<<NUM_G, 64, 0, stream>>>(
            sum_c, sum_b, batch_c, Nc, batch_b, Nb,
            W1, b1, W2, b2, W3, b3, Wout, bout, (float*)d_out);
    }
}

// Round 15
// 470.548 us; speedup vs baseline: 1.0970x; 1.0970x over previous
//
#include <hip/hip_runtime.h>
#include <math.h>

#define H 64
#define F 16
#define NUM_G 128
#define DPW 8
#define NBLK 512     // segments for bucket partition
#define SORTB 256    // dst-range buckets
#define L2E 1.4426950408889634f
#define TWO_L2E 2.8853900817779268f

__device__ __forceinline__ int lower_bound_i(const int* a, int n, int key) {
    int lo = 0, hi = n;
    while (lo < hi) { int mid = (lo + hi) >> 1; if (a[mid] < key) lo = mid + 1; else hi = mid; }
    return lo;
}

__device__ __forceinline__ unsigned bf16rne(float f) {
    unsigned u = __float_as_uint(f);
    return (u + 0x7fffu + ((u >> 16) & 1u)) >> 16;
}

__device__ __forceinline__ unsigned sel8u(unsigned a0, unsigned a1, unsigned a2, unsigned a3,
                                          unsigned a4, unsigned a5, unsigned a6, unsigned a7, int i) {
    unsigned b0 = (i & 1) ? a1 : a0, b1 = (i & 1) ? a3 : a2;
    unsigned b2 = (i & 1) ? a5 : a4, b3 = (i & 1) ? a7 : a6;
    unsigned c0 = (i & 2) ? b1 : b0, c1 = (i & 2) ? b3 : b2;
    return (i & 4) ? c1 : c0;
}
__device__ __forceinline__ int sel8i(int a0, int a1, int a2, int a3,
                                     int a4, int a5, int a6, int a7, int i) {
    int b0 = (i & 1) ? a1 : a0, b1 = (i & 1) ? a3 : a2;
    int b2 = (i & 1) ? a5 : a4, b3 = (i & 1) ? a7 : a6;
    int c0 = (i & 2) ? b1 : b0, c1 = (i & 2) ? b3 : b2;
    return (i & 4) ? c1 : c0;
}

// ---------------- projection section descriptor ----------------
struct ProjSec {
    const float* x; const float* Wa; const float* ba;
    const float* Wb; const float* bb2; unsigned* out;
    int N; int waveOff; float scaleA;
};
#define PROJ_ROWS 16

__device__ __forceinline__ void proj_rows(const ProjSec& S, int w, int lane) {
    const int r0 = (w - S.waveOff) * PROJ_ROWS;
    float wa[F], wb[F];
#pragma unroll
    for (int f = 0; f < F; ++f) {
        wa[f] = S.Wa[f * H + lane] * S.scaleA;
        wb[f] = S.Wb[f * H + lane];
    }
    const float bah = S.ba[lane] * S.scaleA, bbh = S.bb2[lane];
    int r1e = r0 + PROJ_ROWS; if (r1e > S.N) r1e = S.N;
    for (int n = r0; n < r1e; ++n) {
        const float4* xr = (const float4*)(S.x + (size_t)n * F);
        float a = bah, b = bbh;
#pragma unroll
        for (int f4 = 0; f4 < F / 4; ++f4) {
            float4 t = xr[f4];
            a = fmaf(t.x, wa[4*f4+0], a); a = fmaf(t.y, wa[4*f4+1], a);
            a = fmaf(t.z, wa[4*f4+2], a); a = fmaf(t.w, wa[4*f4+3], a);
            b = fmaf(t.x, wb[4*f4+0], b); b = fmaf(t.y, wb[4*f4+1], b);
            b = fmaf(t.z, wb[4*f4+2], b); b = fmaf(t.w, wb[4*f4+3], b);
        }
        S.out[(size_t)n * H + lane] = bf16rne(a) | (bf16rne(b) << 16);
    }
}

// ---------------- fused bucket-histogram (+btot atomics) + 4-section projections ----------------
__global__ __launch_bounds__(256) void bhist_proj_kernel(
    const int* __restrict__ dst0, int E0,
    const int* __restrict__ dst1, int E1n, int dstOff1,
    int perB, int* __restrict__ bhist, int* __restrict__ btot,
    ProjSec s0, ProjSec s1, ProjSec s2, ProjSec s3, int wTot)
{
    if ((int)blockIdx.x < NBLK) {
        __shared__ int c[SORTB];
        if (threadIdx.x < SORTB) c[threadIdx.x] = 0;
        __syncthreads();
        const long ET = (long)E0 + E1n;
        const long e0 = ET * blockIdx.x / NBLK;
        const long e1 = ET * (blockIdx.x + 1) / NBLK;
        for (long i = e0 + threadIdx.x; i < e1; i += 256) {
            int d = (i < E0) ? __builtin_nontemporal_load(dst0 + i)
                             : dstOff1 + __builtin_nontemporal_load(dst1 + (i - E0));
            atomicAdd(&c[(unsigned)d / (unsigned)perB], 1);
        }
        __syncthreads();
        if (threadIdx.x < SORTB) {
            bhist[threadIdx.x * NBLK + blockIdx.x] = c[threadIdx.x];
            atomicAdd(&btot[threadIdx.x], c[threadIdx.x]);
        }
        return;
    }
    const int lane = threadIdx.x & 63;
    const int w = ((int)blockIdx.x - NBLK) * 4 + (threadIdx.x >> 6);
    if (w >= wTot) return;
    ProjSec S = (w >= s3.waveOff) ? s3 : (w >= s2.waveOff) ? s2 : (w >= s1.waveOff) ? s1 : s0;
    proj_rows(S, w, lane);
}

// ---------------- fallback: fused per-dst hist + projections ----------------
__global__ __launch_bounds__(256) void hist_proj_kernel(
    const int* __restrict__ dst0, int E0,
    const int* __restrict__ dst1, int E1n, int dstOff1,
    int* __restrict__ cnt, int histBlocks,
    ProjSec s0, ProjSec s1, ProjSec s2, ProjSec s3, int wTot)
{
    if ((int)blockIdx.x < histBlocks) {
        int i = blockIdx.x * blockDim.x + threadIdx.x;
        if (i < E0) {
            atomicAdd(&cnt[dst0[i]], 1);
        } else {
            i -= E0;
            if (i < E1n) atomicAdd(&cnt[dstOff1 + dst1[i]], 1);
        }
        return;
    }
    const int lane = threadIdx.x & 63;
    const int w = ((int)blockIdx.x - histBlocks) * 4 + (threadIdx.x >> 6);
    if (w >= wTot) return;
    ProjSec S = (w >= s3.waveOff) ? s3 : (w >= s2.waveOff) ? s2 : (w >= s1.waveOff) ? s1 : s0;
    proj_rows(S, w, lane);
}

// ---------------- scan bucket totals (257 entries, in place) ----------------
__global__ __launch_bounds__(256) void btot_scan_kernel(int* __restrict__ bs)
{
    __shared__ int sh[256];
    const int t = threadIdx.x;
    const int v = bs[t];
    sh[t] = v;
    __syncthreads();
    for (int off = 1; off < 256; off <<= 1) {
        int x = sh[t];
        int add = (t >= off) ? sh[t - off] : 0;
        __syncthreads();
        sh[t] = x + add;
        __syncthreads();
    }
    bs[t] = sh[t] - v;              // exclusive
    if (t == 255) bs[256] = sh[255];
}

// ---------------- per-bucket scan over blocks ----------------
__global__ __launch_bounds__(256) void bhist_scan_kernel(int* __restrict__ bhist,
                                                         const int* __restrict__ bucketStart)
{
    const int o = blockIdx.x, t = threadIdx.x;
    int v0 = bhist[o * NBLK + 2 * t];
    int v1 = bhist[o * NBLK + 2 * t + 1];
    __shared__ int part[256];
    part[t] = v0 + v1;
    __syncthreads();
    for (int off = 1; off < 256; off <<= 1) {
        int v = part[t];
        int add = (t >= off) ? part[t - off] : 0;
        __syncthreads();
        part[t] = v + add;
        __syncthreads();
    }
    int excl = (t == 0) ? 0 : part[t - 1];
    const int base = bucketStart[o];
    bhist[o * NBLK + 2 * t] = base + excl;
    bhist[o * NBLK + 2 * t + 1] = base + excl + v0;
}

// ---------------- deterministic bucket partition (8B packed tuples) ----------------
// tuple.x = s | (dlocal << 18)   (requires srcTot < 2^18, perB < 2^11 — checked host-side)
__global__ __launch_bounds__(256) void bscatter_kernel(
    const int* __restrict__ src0, const int* __restrict__ dst0,
    const float* __restrict__ ea0, int E0,
    const int* __restrict__ src1, const int* __restrict__ dst1,
    const float* __restrict__ ea1, int E1n,
    int dstOff1, int srcOff1, int perB,
    const int* __restrict__ bhist,
    int2* __restrict__ t_se)
{
    __shared__ int cur[SORTB];
    if (threadIdx.x < SORTB)
        cur[threadIdx.x] = bhist[threadIdx.x * NBLK + blockIdx.x];
    __syncthreads();
    const long ET = (long)E0 + E1n;
    const long e0 = ET * blockIdx.x / NBLK;
    const long e1 = ET * (blockIdx.x + 1) / NBLK;
    for (long i = e0 + threadIdx.x; i < e1; i += 256) {
        int s, d; float e;
        if (i < E0) {
            s = __builtin_nontemporal_load(src0 + i);
            d = __builtin_nontemporal_load(dst0 + i);
            e = __builtin_nontemporal_load(ea0 + i);
        } else {
            long j = i - E0;
            s = __builtin_nontemporal_load(src1 + j) + srcOff1;
            d = __builtin_nontemporal_load(dst1 + j) + dstOff1;
            e = __builtin_nontemporal_load(ea1 + j);
        }
        int o = (unsigned)d / (unsigned)perB;
        int dlocal = d - o * perB;
        int slot = atomicAdd(&cur[o], 1);     // LDS atomic
        t_se[slot] = make_int2(s | (dlocal << 18), __float_as_int(e));
    }
}

// ---------------- per-bucket LDS sort -> offsets + meta ----------------
__global__ __launch_bounds__(256) void bucket_sort_kernel(
    const int2* __restrict__ t_se,
    const int* __restrict__ bucketStart, int NT, int perB,
    int* __restrict__ offsets, int2* __restrict__ meta)
{
    extern __shared__ int lds[];     // cnt[perB] | part[256]
    int* cnt = lds;
    int* part = lds + perB;
    const int o = blockIdx.x, t = threadIdx.x;
    int dlo = o * perB; if (dlo > NT) dlo = NT;
    int dhi = dlo + perB; if (dhi > NT) dhi = NT;
    const int nd = dhi - dlo;
    for (int i = t; i < nd; i += 256) cnt[i] = 0;
    __syncthreads();
    const int b0 = bucketStart[o], b1 = bucketStart[o + 1];
    for (int i = b0 + t; i < b1; i += 256)
        atomicAdd(&cnt[(unsigned)t_se[i].x >> 18], 1);
    __syncthreads();
    const int C = (nd + 255) / 256;
    const int lo = t * C;
    int hi = lo + C; if (hi > nd) hi = nd;
    int s = 0;
    for (int j = lo; j < hi; ++j) s += cnt[j];
    part[t] = s;
    __syncthreads();
    for (int off = 1; off < 256; off <<= 1) {
        int v = part[t];
        int add = (t >= off) ? part[t - off] : 0;
        __syncthreads();
        part[t] = v + add;
        __syncthreads();
    }
    int run = (t == 0) ? 0 : part[t - 1];
    for (int j = lo; j < hi; ++j) { int v = cnt[j]; cnt[j] = run; run += v; }
    __syncthreads();
    for (int i = t; i < nd; i += 256) offsets[dlo + i] = b0 + cnt[i];
    if (dhi == NT && t == 0) offsets[NT] = b1;
    __syncthreads();
    for (int i = b0 + t; i < b1; i += 256) {
        int2 se = t_se[i];
        int dl = (unsigned)se.x >> 18;
        int slot = b0 + atomicAdd(&cnt[dl], 1);
        meta[slot] = make_int2(se.x & 0x3FFFF, se.y);
    }
}

// ---------------- fallback global scan + scatter ----------------
__global__ __launch_bounds__(256) void scan_partial(const int* __restrict__ cnt,
                                                    int* __restrict__ bsums, int n) {
    __shared__ int red[256];
    const int b = blockIdx.x, t = threadIdx.x;
    const int base = b * 2048 + t * 8;
    int s = 0;
#pragma unroll
    for (int i = 0; i < 8; ++i) { int idx = base + i; if (idx < n) s += cnt[idx]; }
    red[t] = s;
    __syncthreads();
    for (int off = 128; off > 0; off >>= 1) {
        if (t < off) red[t] += red[t + off];
        __syncthreads();
    }
    if (t == 0) bsums[b] = red[0];
}

__global__ __launch_bounds__(256) void scan_bsums(int* __restrict__ bsums, int nb) {
    __shared__ int sh[256];
    const int t = threadIdx.x;
    sh[t] = (t < nb) ? bsums[t] : 0;
    __syncthreads();
    for (int off = 1; off < 256; off <<= 1) {
        int v = sh[t];
        int add = (t >= off) ? sh[t - off] : 0;
        __syncthreads();
        sh[t] = v + add;
        __syncthreads();
    }
    if (t < nb) bsums[t] = (t == 0) ? 0 : sh[t - 1];
}

__global__ __launch_bounds__(256) void scan_final(int* __restrict__ cnt,
                                                  const int* __restrict__ bsums,
                                                  int* __restrict__ offsets, int n) {
    __shared__ int red[256];
    const int b = blockIdx.x, t = threadIdx.x;
    const int base = b * 2048 + t * 8;
    int v[8]; int s = 0;
#pragma unroll
    for (int i = 0; i < 8; ++i) { int idx = base + i; v[i] = (idx < n) ? cnt[idx] : 0; s += v[i]; }
    red[t] = s;
    __syncthreads();
    for (int off = 1; off < 256; off <<= 1) {
        int val = red[t];
        int add = (t >= off) ? red[t - off] : 0;
        __syncthreads();
        red[t] = val + add;
        __syncthreads();
    }
    const int ex = (t == 0) ? 0 : red[t - 1];
    int run = bsums[b] + ex;
#pragma unroll
    for (int i = 0; i < 8; ++i) {
        int idx = base + i;
        if (idx < n) { offsets[idx] = run; cnt[idx] = run; }
        run += v[i];
    }
    if (t == 255 && b == gridDim.x - 1) offsets[n] = run;
}

__device__ __forceinline__ void scat_sub(
    const int* __restrict__ src, const int* __restrict__ dst,
    const float* __restrict__ ea, long lo, long hi,
    int dstOff, int srcOff, int dlo, int dhi,
    int* __restrict__ cursor, int2* __restrict__ meta, int tid)
{
    for (long i = lo + tid; i < hi; i += 256) {
        int d = dstOff + __builtin_nontemporal_load(dst + i);
        if (d >= dlo && d < dhi) {
            int s = __builtin_nontemporal_load(src + i) + srcOff;
            float e = __builtin_nontemporal_load(ea + i);
            int p = atomicAdd(&cursor[d], 1);
            meta[p] = make_int2(s, __float_as_int(e));
        }
    }
}

__global__ __launch_bounds__(256) void scatter_part_kernel(
    const int* __restrict__ src0, const int* __restrict__ dst0,
    const float* __restrict__ ea0, int E0,
    const int* __restrict__ src1, const int* __restrict__ dst1,
    const float* __restrict__ ea1, int E1n,
    int dstOff1, int srcOff1, int NTd,
    int* __restrict__ cursor, int2* __restrict__ meta)
{
    const int grp = blockIdx.x & 7;
    const int seg = blockIdx.x >> 3;
    const int nseg = gridDim.x >> 3;
    const int per = (NTd + 7) >> 3;
    const int dlo = grp * per;
    int dhi = dlo + per; if (dhi > NTd) dhi = NTd;
    if (dlo >= dhi) return;
    const long ET = (long)E0 + E1n;
    const long e0 = (ET * seg) / nseg;
    const long e1 = (ET * (seg + 1)) / nseg;
    const int tid = threadIdx.x;
    long a0 = e0, a1 = (e1 < E0) ? e1 : E0;
    if (a0 < a1) scat_sub(src0, dst0, ea0, a0, a1, 0, 0, dlo, dhi, cursor, meta, tid);
    long b0 = (e0 > E0) ? e0 : E0, b1 = e1;
    if (b0 < b1) scat_sub(src1, dst1, ea1, b0 - E0, b1 - E0, dstOff1, srcOff1,
                          dlo, dhi, cursor, meta, tid);
}

// ---------------- deep-pipelined streaming aggregate (R11 schedule: 2-deep ring) ----------------
struct RelP {
    const float* We; const float* be;
    const int* batch;
    float* psum;
    int Ndst;
    int offBase;
    int kskBase;
};

__global__ __launch_bounds__(256) void aggregate_v4(
    RelP P0, RelP P1, const unsigned* __restrict__ qvp,
    const unsigned* __restrict__ kskp,
    const int* __restrict__ offsets, const int2* __restrict__ meta,
    int nChunk0, int chunkHi)
{
    const int lane = threadIdx.x & 63;
    const int cid = blockIdx.x * (blockDim.x >> 6) + (threadIdx.x >> 6);
    if (cid >= chunkHi) return;
    const bool r1v = (cid >= nChunk0);
    const RelP P = r1v ? P1 : P0;
    const int dLo = (r1v ? cid - nChunk0 : cid) * DPW;
    if (dLo >= P.Ndst) return;
    const int ndst = (P.Ndst - dLo < DPW) ? (P.Ndst - dLo) : DPW;

    const float weh = P.We[lane], beh = P.be[lane];

    const int* ob = offsets + P.offBase + dLo;
    const int* bb_ = P.batch + dLo;
    int of0, of1, of2, of3, of4, of5, of6, of7, of8;
    int bg0, bg1, bg2, bg3, bg4, bg5, bg6, bg7;
#define LDO(I) __builtin_amdgcn_readfirstlane(ob[(I) < ndst ? (I) : ndst])
#define LDB(I) __builtin_amdgcn_readfirstlane(bb_[(I) < ndst ? (I) : (ndst - 1)])
    of0 = LDO(0); of1 = LDO(1); of2 = LDO(2); of3 = LDO(3); of4 = LDO(4);
    of5 = LDO(5); of6 = LDO(6); of7 = LDO(7); of8 = LDO(8);
    bg0 = LDB(0); bg1 = LDB(1); bg2 = LDB(2); bg3 = LDB(3);
    bg4 = LDB(4); bg5 = LDB(5); bg6 = LDB(6); bg7 = LDB(7);
#undef LDO
#undef LDB

    const unsigned* kb = kskp + (size_t)(P.kskBase + dLo) * H + lane;
    unsigned kp0 = kb[0], kp1 = 0, kp2 = 0, kp3 = 0, kp4 = 0, kp5 = 0, kp6 = 0, kp7 = 0;
    if (ndst > 1) kp1 = kb[1 * H];
    if (ndst > 2) kp2 = kb[2 * H];
    if (ndst > 3) kp3 = kb[3 * H];
    if (ndst > 4) kp4 = kb[4 * H];
    if (ndst > 5) kp5 = kb[5 * H];
    if (ndst > 6) kp6 = kb[6 * H];
    if (ndst > 7) kp7 = kb[7 * H];

    int idx = 0;
    float kcur = __uint_as_float(kp0 << 16);
    float skcur = __uint_as_float(kp0 & 0xffff0000u);
    int pend = of1;
    int bgcur = bg0;
    float acc = 0.f;
    const int base = of0;
    const int pstop = of8;
    const int nedges = pstop - base;
    const int ngroups = (nedges + 7) >> 3;

#define ADVANCE()                                                              \
    {                                                                          \
        float hv = fmaxf(acc + skcur, 0.f);                                    \
        atomicAdd(&P.psum[(size_t)bgcur * H + lane], hv);                      \
        ++idx;                                                                 \
        unsigned kv = sel8u(kp0, kp1, kp2, kp3, kp4, kp5, kp6, kp7, idx);      \
        kcur = __uint_as_float(kv << 16);                                      \
        skcur = __uint_as_float(kv & 0xffff0000u);                             \
        pend = sel8i(of1, of2, of3, of4, of5, of6, of7, of8, idx);             \
        bgcur = sel8i(bg0, bg1, bg2, bg3, bg4, bg5, bg6, bg7, idx);            \
        acc = 0.f;                                                             \
    }

#define ISSUE(RING, M, L8, GI)                                                 \
    if ((GI) < ngroups) {                                                      \
        _Pragma("unroll")                                                      \
        for (int j = 0; j < 8; ++j) {                                          \
            int s_ = __builtin_amdgcn_readlane((M).x, (L8) + j);               \
            RING[j] = qvp[(size_t)(unsigned)s_ * H + lane];                    \
        }                                                                      \
    }

#define CONSUME(RING, L8, GI)                                                  \
    if ((GI) < ngroups) {                                                      \
        const int e0 = (GI) * 8;                                               \
        int n_ = nedges - e0; if (n_ > 8) n_ = 8;                              \
        _Pragma("unroll")                                                      \
        for (int j = 0; j < 8; ++j) {                                          \
            if (j < n_) {                                                      \
                while (base + e0 + j >= pend) ADVANCE();                       \
                float e = fmaf(__int_as_float(                                 \
                    __builtin_amdgcn_readlane(Mc.y, (L8) + j)), weh, beh);     \
                float qq = __uint_as_float(RING[j] << 16);                     \
                float vv = __uint_as_float(RING[j] & 0xffff0000u);             \
                float g2 = fmaf(TWO_L2E, e, kcur + qq);                        \
                float sg = __builtin_amdgcn_rcpf(1.0f + __builtin_amdgcn_exp2f(-g2)); \
                acc = fmaf(sg, vv + e, acc);                                   \
            }                                                                  \
        }                                                                      \
    }

    if (nedges > 0) {
        int pos0 = base + lane; if (pos0 > pstop - 1) pos0 = pstop - 1;
        int2 Mc = meta[pos0];
        int2 Mn = Mc;
        if (nedges > 64) {
            int pos1 = base + 64 + lane; if (pos1 > pstop - 1) pos1 = pstop - 1;
            Mn = meta[pos1];
        }
        unsigned r0[8], r1[8], r2[8], r3[8];
        ISSUE(r0, Mc, 0, 0);
        ISSUE(r1, Mc, 8, 1);
        const int nsb = (ngroups + 7) >> 3;
        int sbg = 0;
        for (int sbi = 0; sbi < nsb; ++sbi, sbg += 8) {
            ISSUE(r2, Mc, 16, sbg + 2); CONSUME(r0, 0,  sbg + 0);
            ISSUE(r3, Mc, 24, sbg + 3); CONSUME(r1, 8,  sbg + 1);
            ISSUE(r0, Mc, 32, sbg + 4); CONSUME(r2, 16, sbg + 2);
            ISSUE(r1, Mc, 40, sbg + 5); CONSUME(r3, 24, sbg + 3);
            ISSUE(r2, Mc, 48, sbg + 6); CONSUME(r0, 32, sbg + 4);
            ISSUE(r3, Mc, 56, sbg + 7); CONSUME(r1, 40, sbg + 5);
            ISSUE(r0, Mn, 0,  sbg + 8); CONSUME(r2, 48, sbg + 6);
            ISSUE(r1, Mn, 8,  sbg + 9); CONSUME(r3, 56, sbg + 7);
            Mc = Mn;
            if ((sbi + 2) * 64 < nedges) {
                int pos = base + (sbi + 2) * 64 + lane;
                if (pos > pstop - 1) pos = pstop - 1;
                Mn = meta[pos];
            }
        }
    }
#undef ISSUE
#undef CONSUME

    for (;;) {
        float hv = fmaxf(acc + skcur, 0.f);
        atomicAdd(&P.psum[(size_t)bgcur * H + lane], hv);
        ++idx;
        if (idx >= ndst) break;
        unsigned kv = sel8u(kp0, kp1, kp2, kp3, kp4, kp5, kp6, kp7, idx);
        kcur = __uint_as_float(kv << 16);
        skcur = __uint_as_float(kv & 0xffff0000u);
        bgcur = sel8i(bg0, bg1, bg2, bg3, bg4, bg5, bg6, bg7, idx);
        acc = 0.f;
    }
#undef ADVANCE
}

// ---------------- MLP with fused per-graph counts ----------------
__global__ __launch_bounds__(64) void mlp_kernel(
    const float* __restrict__ sum_c, const float* __restrict__ sum_b,
    const int* __restrict__ batch_c, int Nc,
    const int* __restrict__ batch_b, int Nb,
    const float* __restrict__ W1, const float* __restrict__ b1,
    const float* __restrict__ W2, const float* __restrict__ b2,
    const float* __restrict__ W3, const float* __restrict__ b3,
    const float* __restrict__ Wout, const float* __restrict__ bout,
    float* __restrict__ out)
{
    const int g = blockIdx.x;
    const int h = threadIdx.x;
    __shared__ float pld[2 * H];
    __shared__ float hbuf[H];
    __shared__ float cnts[2];
    if (h < 2) {
        const int* a = h ? batch_b : batch_c;
        const int n = h ? Nb : Nc;
        int lo = lower_bound_i(a, n, g);
        int hi = lower_bound_i(a, n, g + 1);
        cnts[h] = fmaxf((float)(hi - lo), 1.f);
    }
    __syncthreads();
    pld[h] = sum_c[g * H + h] / cnts[0];
    pld[H + h] = sum_b[g * H + h] / cnts[1];
    __syncthreads();
    float a1 = b1[h];
    for (int j = 0; j < 2 * H; ++j) a1 = fmaf(pld[j], W1[j * H + h], a1);
    a1 = fmaxf(a1, 0.f);
    __syncthreads();
    hbuf[h] = a1;
    __syncthreads();
    float a2 = b2[h];
    for (int j = 0; j < H; ++j) a2 = fmaf(hbuf[j], W2[j * H + h], a2);
    a2 = fmaxf(a2, 0.f);
    __syncthreads();
    hbuf[h] = a2;
    __syncthreads();
    float a3 = b3[h];
    for (int j = 0; j < H; ++j) a3 = fmaf(hbuf[j], W3[j * H + h], a3);
    a3 = fmaxf(a3, 0.f);
    float p = a3 * Wout[h];
#pragma unroll
    for (int off = 32; off > 0; off >>= 1) p += __shfl_down(p, off, 64);
    if (h == 0) out[g] = p + bout[0];
}

extern "C" void kernel_launch(void* const* d_in, const int* in_sizes, int n_in,
                              void* d_out, int out_size, void* d_ws, size_t ws_size,
                              hipStream_t stream) {
    const float* x_x   = (const float*)d_in[0];
    const float* x_c   = (const float*)d_in[1];
    const float* x_b   = (const float*)d_in[2];
    const float* ea_ac = (const float*)d_in[3];
    const float* ea_cb = (const float*)d_in[4];

    const float* Wk_ac = (const float*)d_in[5];
    const float* Wq_ac = (const float*)d_in[6];
    const float* Wv_ac = (const float*)d_in[7];
    const float* Wskip_ac = (const float*)d_in[8];
    const float* We_ac = (const float*)d_in[9];
    const float* bk_ac = (const float*)d_in[10];
    const float* bq_ac = (const float*)d_in[11];
    const float* bv_ac = (const float*)d_in[12];
    const float* be_ac = (const float*)d_in[13];
    const float* bconv_ac = (const float*)d_in[14];

    const float* Wk_cb = (const float*)d_in[15];
    const float* Wq_cb = (const float*)d_in[16];
    const float* Wv_cb = (const float*)d_in[17];
    const float* Wskip_cb = (const float*)d_in[18];
    const float* We_cb = (const float*)d_in[19];
    const float* bk_cb = (const float*)d_in[20];
    const float* bq_cb = (const float*)d_in[21];
    const float* bv_cb = (const float*)d_in[22];
    const float* be_cb = (const float*)d_in[23];
    const float* bconv_cb = (const float*)d_in[24];

    const float* W1 = (const float*)d_in[25];
    const float* b1 = (const float*)d_in[26];
    const float* W2 = (const float*)d_in[27];
    const float* b2 = (const float*)d_in[28];
    const float* W3 = (const float*)d_in[29];
    const float* b3 = (const float*)d_in[30];
    const float* Wout = (const float*)d_in[31];
    const float* bout = (const float*)d_in[32];

    const int* src_ac = (const int*)d_in[33];
    const int* dst_ac = (const int*)d_in[34];
    const int* src_cb = (const int*)d_in[35];
    const int* dst_cb = (const int*)d_in[36];
    const int* batch_c = (const int*)d_in[37];
    const int* batch_b = (const int*)d_in[38];

    const int Nx = in_sizes[0] / F;
    const int Nc = in_sizes[1] / F;
    const int Nb = in_sizes[2] / F;
    const int E1 = in_sizes[33];
    const int E2 = in_sizes[35];
    (void)n_in; (void)out_size;

    const int NT = Nc + Nb;
    const size_t ET = (size_t)E1 + E2;
    const size_t SUMS = 2 * NUM_G * H;
    const int perB = (NT + SORTB - 1) / SORTB;

    const size_t qvW  = (size_t)(Nx + Nc) * H;
    const size_t kskW = (size_t)(Nc + Nb) * H;
    const size_t head = 2 * ET + (size_t)(NT + 1) + 257 + SUMS + qvW + kskW;
    const size_t tOff = (head + 1) & ~(size_t)1;
    const size_t wordsB = tOff + 2 * ET + (size_t)SORTB * NBLK;
    const size_t wordsA = head + (size_t)NT + 256;      // fallback overlays cnt/bsums
    const bool packOK = ((Nx + Nc) <= (1 << 18)) && (perB <= (1 << 11));
    const bool pathA = (ws_size >= wordsA * 4);
    const bool pathB = (ws_size >= wordsB * 4) && packOK;

    int* ws = (int*)d_ws;
    int2*     meta        = (int2*)ws;
    int*      offsets     = ws + 2 * ET;
    int*      bucketStart = offsets + (NT + 1);
    float*    sum_c       = (float*)(bucketStart + 257);
    float*    sum_b       = sum_c + NUM_G * H;
    unsigned* qvp         = (unsigned*)(sum_b + NUM_G * H);
    unsigned* kskp        = qvp + qvW;
    int2*     t_se        = (int2*)(ws + tOff);
    int*      bhist       = (int*)(t_se + ET);
    int*      cnt         = (int*)t_se;          // fallback overlay
    int*      bsums       = cnt + NT;            // fallback overlay

    const int nC0 = (Nc + DPW - 1) / DPW;
    const int nC1 = (Nb + DPW - 1) / DPW;

    RelP P0, P1;
    P0.We = We_ac; P0.be = be_ac; P0.batch = batch_c; P0.psum = sum_c;
    P0.Ndst = Nc; P0.offBase = 0; P0.kskBase = 0;
    P1.We = We_cb; P1.be = be_cb; P1.batch = batch_b; P1.psum = sum_b;
    P1.Ndst = Nb; P1.offBase = Nc; P1.kskBase = Nc;

    if (pathA) {
        const int w1 = (Nx + PROJ_ROWS - 1) / PROJ_ROWS;
        const int w2 = w1 + (Nc + PROJ_ROWS - 1) / PROJ_ROWS;
        const int w3 = w2 + (Nc + PROJ_ROWS - 1) / PROJ_ROWS;
        const int wTot = w3 + (Nb + PROJ_ROWS - 1) / PROJ_ROWS;
        ProjSec s0 = { x_x, Wq_ac, bq_ac, Wv_ac, bv_ac, qvp, Nx, 0, L2E };
        ProjSec s1 = { x_c, Wq_cb, bq_cb, Wv_cb, bv_cb, qvp + (size_t)Nx * H, Nc, w1, L2E };
        ProjSec s2 = { x_c, Wk_ac, bk_ac, Wskip_ac, bconv_ac, kskp, Nc, w2, L2E };
        ProjSec s3 = { x_b, Wk_cb, bk_cb, Wskip_cb, bconv_cb, kskp + (size_t)Nc * H, Nb, w3, L2E };
        const int projB = (wTot + 3) / 4;

        if (pathB) {
            hipMemsetAsync(bucketStart, 0, (257 + SUMS) * sizeof(int), stream);
            bhist_proj_kernel<<<NBLK + projB, 256, 0, stream>>>(
                dst_ac, E1, dst_cb, E2, Nc, perB, bhist, bucketStart,
                s0, s1, s2, s3, wTot);
            btot_scan_kernel<<<1, 256, 0, stream>>>(bucketStart);
            bhist_scan_kernel<<<SORTB, 256, 0, stream>>>(bhist, bucketStart);
            bscatter_kernel<<<NBLK, 256, 0, stream>>>(
                src_ac, dst_ac, ea_ac, E1, src_cb, dst_cb, ea_cb, E2,
                Nc, Nx, perB, bhist, t_se);
            bucket_sort_kernel<<<SORTB, 256, (perB + 257) * sizeof(int), stream>>>(
                t_se, bucketStart, NT, perB, offsets, meta);
        } else {
            hipMemsetAsync(bucketStart, 0, (257 + SUMS) * sizeof(int), stream);
            hipMemsetAsync(cnt, 0, (size_t)(NT + 256) * sizeof(int), stream);
            const int nScan = (NT + 2047) / 2048;
            const int EB = (int)((ET + 255) / 256);
            hist_proj_kernel<<<EB + projB, 256, 0, stream>>>(
                dst_ac, E1, dst_cb, E2, Nc, cnt, EB, s0, s1, s2, s3, wTot);
            scan_partial<<<nScan, 256, 0, stream>>>(cnt, bsums, NT);
            scan_bsums<<<1, 256, 0, stream>>>(bsums, nScan);
            scan_final<<<nScan, 256, 0, stream>>>(cnt, bsums, offsets, NT);
            scatter_part_kernel<<<2048, 256, 0, stream>>>(
                src_ac, dst_ac, ea_ac, E1, src_cb, dst_cb, ea_cb, E2,
                Nc, Nx, NT, cnt, meta);
        }

        const int nW = nC0 + nC1;
        aggregate_v4<<<(nW + 3) / 4, 256, 0, stream>>>(
            P0, P1, qvp, kskp, offsets, meta, nC0, nW);

        mlp_kernel<<<NUM_G, 64, 0, stream>>>(
            sum_c, sum_b, batch_c, Nc, batch_b, Nb,
            W1, b1, W2, b2, W3, b3, Wout, bout, (float*)d_out);
    }
}